// Round 1
// baseline (96970.349 us; speedup 1.0000x reference)
//
#include <hip/hip_runtime.h>
#include <hip/hip_cooperative_groups.h>

namespace cg = cooperative_groups;

typedef unsigned short u16;
typedef __attribute__((ext_vector_type(8))) short bf16x8;
typedef __attribute__((ext_vector_type(4))) float f32x4;

#define TOUT 500
#define KATT 1792
#define KDEC 2560

// ---------------- workspace layout (bytes) ----------------
constexpr size_t OW_ATT = 0;                                   // bf16 [4096][1792]
constexpr size_t OW_DEC = OW_ATT + (size_t)4096*KATT*2;        // bf16 [4096][2560]
constexpr size_t OMEMB  = OW_DEC + (size_t)4096*KDEC*2;        // bf16 [32*512][512] memory
constexpr size_t OPMB   = OMEMB + (size_t)32*512*512*2;        // bf16 [32*512][128] pm
constexpr size_t OPREB  = OPMB + (size_t)32*512*128*2;         // bf16 [500*32][256] prenet out
constexpr size_t OWMB   = OPREB + (size_t)500*32*256*2;        // bf16 [128][512] wm
constexpr size_t OW1B   = OWMB + (size_t)128*512*2;            // bf16 [256][96] prenet w1 (padded)
constexpr size_t OW2B   = OW1B + (size_t)256*96*2;             // bf16 [256][256] prenet w2
constexpr size_t OAXB   = OW2B + (size_t)256*256*2;            // bf16 [16000][96] prenet input
constexpr size_t OH1B   = OAXB + (size_t)16000*96*2;           // bf16 [16000][256] prenet hidden
constexpr size_t OBLOC  = OH1B + (size_t)16000*256*2;          // bf16 [128][64] merged loc kernel
constexpr size_t OPGW   = OBLOC + (size_t)128*64*2;            // bf16 [96][1536] proj+gate weights
constexpr size_t OAATT  = OPGW + (size_t)96*1536*2;            // bf16 [32][1792]  (pre|actx|ah)
constexpr size_t OADEC  = OAATT + (size_t)32*KATT*2;           // bf16 [32][2560]  (ah|actx|dh)
constexpr size_t OAPROJ = OADEC + (size_t)32*KDEC*2;           // bf16 [2][32][1536] (dh|actx) dbuf
constexpr size_t OALOC  = OAPROJ + (size_t)2*32*1536*2;        // bf16 [16384][64] loc GEMM A
constexpr size_t OLOCB  = OALOC + (size_t)16384*64*2;          // bf16 [16384][128] loc GEMM out
constexpr size_t OGATT  = OLOCB + (size_t)16384*128*2;         // f32 [32][4096] att gates
constexpr size_t OGDEC  = OGATT + (size_t)32*4096*4;           // f32 [32][4096] dec gates
constexpr size_t OAC    = OGDEC + (size_t)32*4096*4;           // f32 [32][1024]
constexpr size_t ODC    = OAC + (size_t)32*1024*4;             // f32 [32][1024]
constexpr size_t OAW2   = ODC + (size_t)32*1024*4;             // f32 [32][512]
constexpr size_t OAWC   = OAW2 + (size_t)32*512*4;             // f32 [32][512]
constexpr size_t OEND   = OAWC + (size_t)32*512*4;

#define DI __device__ __forceinline__

DI float bf2f(u16 u){ union {float f; unsigned i;} x; x.i = ((unsigned)u)<<16; return x.f; }
DI u16 f2bf(float f){ union {float f; unsigned i;} x; x.f = f; unsigned r = x.i + 0x7FFFu + ((x.i>>16)&1u); return (u16)(r>>16); }
DI float sigm(float x){ return 1.f/(1.f+__expf(-x)); }
DI float tanhx(float x){ float e = __expf(2.f*x); return 1.f - 2.f/(e+1.f); }

// C-tile GEMM: D[16m x 16n] += A[m0..][K] * B^T, B given as [n][k] row-major.
// k-slot mapping is an arbitrary-but-consistent bijection (contiguous 8/lane-group),
// which is valid because the MFMA pairs identical A/B k-slots.
DI f32x4 gemm_tile(const u16* A, int lda, const u16* Bw, int ldb,
                   int m0, int n0, int K, f32x4 acc) {
  int ln = threadIdx.x & 63;
  const u16* ap = A + (size_t)(m0 + (ln&15))*lda + 8*(ln>>4);
  const u16* bp = Bw + (size_t)(n0 + (ln&15))*ldb + 8*(ln>>4);
  for (int k = 0; k < K; k += 32) {
    bf16x8 av = *(const bf16x8*)(ap + k);
    bf16x8 bv = *(const bf16x8*)(bp + k);
    acc = __builtin_amdgcn_mfma_f32_16x16x32_bf16(av, bv, acc, 0, 0, 0);
  }
  return acc;
}

// ---------------- prep kernels ----------------
__global__ void k_build_watt(char* ws, const float* wih, const float* whh){
  u16* W = (u16*)(ws + OW_ATT);
  int n = blockIdx.x;
  for (int k = threadIdx.x; k < KATT; k += 256) {
    float v = (k < 768) ? wih[(size_t)n*768 + k] : whh[(size_t)n*1024 + (k-768)];
    W[(size_t)n*KATT + k] = f2bf(v);
  }
}
__global__ void k_build_wdec(char* ws, const float* wih, const float* whh){
  u16* W = (u16*)(ws + OW_DEC);
  int n = blockIdx.x;
  for (int k = threadIdx.x; k < KDEC; k += 256) {
    float v = (k < 1536) ? wih[(size_t)n*1536 + k] : whh[(size_t)n*1024 + (k-1536)];
    W[(size_t)n*KDEC + k] = f2bf(v);
  }
}
__global__ void k_cvt(u16* dst, const float* src, long n){
  for (long i = (long)blockIdx.x*256 + threadIdx.x; i < n; i += (long)gridDim.x*256)
    dst[i] = f2bf(src[i]);
}
__global__ void k_build_w1(char* ws, const float* w1){
  u16* W = (u16*)(ws + OW1B);
  int n = blockIdx.x; int k = threadIdx.x;
  if (k < 96) W[n*96 + k] = f2bf(k < 80 ? w1[n*80 + k] : 0.f);
}
__global__ void k_build_pgw(char* ws, const float* pw, const float* gw){
  u16* W = (u16*)(ws + OPGW);
  int n = blockIdx.x; // 96 rows: 0..79 proj, 80 gate, 81..95 zero
  for (int k = threadIdx.x; k < 1536; k += 256) {
    float v = 0.f;
    if (n < 80) v = pw[(size_t)n*1536 + k];
    else if (n == 80) v = gw[k];
    W[(size_t)n*1536 + k] = f2bf(v);
  }
}
__global__ void k_build_ax(char* ws, const float* mels){
  u16* AX = (u16*)(ws + OAXB);
  long ntot = 16000L*96;
  for (long i = (long)blockIdx.x*256 + threadIdx.x; i < ntot; i += (long)gridDim.x*256) {
    int r = (int)(i/96), k = (int)(i%96);
    int tt = r >> 5, b = r & 31;
    float v = 0.f;
    if (k < 80 && tt > 0) v = mels[((size_t)b*80 + k)*500 + (tt-1)];
    AX[i] = f2bf(v);
  }
}
__global__ void k_build_mk(char* ws, const float* ldw, const float* lcw){
  u16* Bl = (u16*)(ws + OBLOC);
  int i = blockIdx.x*256 + threadIdx.x;
  if (i < 128*64) {
    int a = i >> 6, k = i & 63;
    float s = 0.f;
    if (k < 62) {
      int c = k/31, dk = k%31;
      for (int f = 0; f < 32; ++f) s += ldw[a*32+f]*lcw[(f*2 + c)*31 + dk];
    }
    Bl[i] = f2bf(s);
  }
}
// generic prep GEMM: grid.x = #m-tiles; wave w does n-tiles w, w+4, ...
__global__ void k_gemm_pre(const u16* A, int lda, const u16* Bw, int ldb,
                           int NT, int K, u16* C, int ldc, int relu){
  int mt = blockIdx.x; int wv = threadIdx.x>>6, ln = threadIdx.x&63;
  for (int nt = wv; nt < NT; nt += 4) {
    f32x4 acc = {0.f,0.f,0.f,0.f};
    acc = gemm_tile(A, lda, Bw, ldb, mt*16, nt*16, K, acc);
    int r = mt*16 + ((ln>>4)<<2), c = nt*16 + (ln&15);
    #pragma unroll
    for (int i = 0; i < 4; ++i) {
      float v = acc[i];
      if (relu) v = fmaxf(v, 0.f);
      C[(size_t)(r+i)*ldc + c] = f2bf(v);
    }
  }
}
__global__ void k_zero(char* ws){
  size_t n = (OEND - OAATT)/16;
  uint4* p = (uint4*)(ws + OAATT);
  uint4 z; z.x=0; z.y=0; z.z=0; z.w=0;
  for (size_t i = (size_t)blockIdx.x*256 + threadIdx.x; i < n; i += (size_t)gridDim.x*256) p[i] = z;
}
__global__ void k_pre0(char* ws){
  u16* AATT = (u16*)(ws+OAATT);
  const u16* PREB = (const u16*)(ws+OPREB);
  int b = blockIdx.x;
  AATT[(size_t)b*KATT + threadIdx.x] = PREB[(size_t)b*256 + threadIdx.x];
}

// ---------------- main persistent cooperative kernel ----------------
__global__ void __launch_bounds__(256)
k_main(char* ws, const float* wq, const float* vv,
       const float* abih, const float* abhh, const float* dbih, const float* dbhh,
       const float* pb, const float* gb, float* out)
{
  const u16* WATT = (const u16*)(ws + OW_ATT);
  const u16* WDEC = (const u16*)(ws + OW_DEC);
  const u16* MEMB = (const u16*)(ws + OMEMB);
  const u16* PMB  = (const u16*)(ws + OPMB);
  const u16* PREB = (const u16*)(ws + OPREB);
  const u16* BLOC = (const u16*)(ws + OBLOC);
  const u16* PGW  = (const u16*)(ws + OPGW);
  u16* AATT = (u16*)(ws + OAATT);
  u16* ADEC = (u16*)(ws + OADEC);
  u16* APROJ= (u16*)(ws + OAPROJ);
  u16* ALOC = (u16*)(ws + OALOC);
  u16* LOCB = (u16*)(ws + OLOCB);
  float* GATT = (float*)(ws + OGATT);
  float* GDEC = (float*)(ws + OGDEC);
  float* AC  = (float*)(ws + OAC);
  float* DC  = (float*)(ws + ODC);
  float* AW2 = (float*)(ws + OAW2);
  float* AWC = (float*)(ws + OAWC);
  float* out_mel  = out;            // [32][80][500]
  float* out_gate = out + 1280000;  // [32][500]
  float* out_aln  = out + 1296000;  // [32][500][512]

  cg::grid_group grid = cg::this_grid();
  const int bid = blockIdx.x, tid = threadIdx.x;
  const int wv = tid>>6, ln = tid&63;

  __shared__ float sAh[1024];
  __shared__ float sPq[2][128];
  __shared__ float sE[512];
  __shared__ float sRed[256];
  __shared__ float sC[8][32];

  for (int t = 0; t <= TOUT; ++t) {
    // ================= phase G : batched MFMA GEMMs =================
    {
      int gw = bid*4 + wv;  // 0..1023
      if (gw < 512) {
        if (t < TOUT) { // attention-LSTM gates, step t
          int nt = gw >> 1, mt = gw & 1;
          f32x4 acc = {0.f,0.f,0.f,0.f};
          acc = gemm_tile(AATT, KATT, WATT, KATT, mt*16, nt*16, KATT, acc);
          int r = mt*16 + ((ln>>4)<<2), c = nt*16 + (ln&15);
          #pragma unroll
          for (int i = 0; i < 4; ++i) GATT[(size_t)(r+i)*4096 + c] = acc[i];
        }
      } else {
        if (t >= 1) { // decoder-LSTM gates, step t-1
          int dwv = gw - 512;
          int nt = dwv >> 1, mt = dwv & 1;
          f32x4 acc = {0.f,0.f,0.f,0.f};
          acc = gemm_tile(ADEC, KDEC, WDEC, KDEC, mt*16, nt*16, KDEC, acc);
          int r = mt*16 + ((ln>>4)<<2), c = nt*16 + (ln&15);
          #pragma unroll
          for (int i = 0; i < 4; ++i) GDEC[(size_t)(r+i)*4096 + c] = acc[i];
        }
      }
      if (t < TOUT) { // merged location conv+dense GEMM, step t
        int q = gw; // m-tile over (b,t_in) rows
        const u16* ar = ALOC + (size_t)(q*16 + (ln&15))*64 + 8*(ln>>4);
        bf16x8 a0 = *(const bf16x8*)(ar);
        bf16x8 a1 = *(const bf16x8*)(ar + 32);
        int r = q*16 + ((ln>>4)<<2);
        for (int nt = 0; nt < 8; ++nt) {
          const u16* br = BLOC + (size_t)(nt*16 + (ln&15))*64 + 8*(ln>>4);
          bf16x8 b0 = *(const bf16x8*)(br);
          bf16x8 b1 = *(const bf16x8*)(br + 32);
          f32x4 acc = {0.f,0.f,0.f,0.f};
          acc = __builtin_amdgcn_mfma_f32_16x16x32_bf16(a0, b0, acc, 0,0,0);
          acc = __builtin_amdgcn_mfma_f32_16x16x32_bf16(a1, b1, acc, 0,0,0);
          int c = nt*16 + (ln&15);
          #pragma unroll
          for (int i = 0; i < 4; ++i) LOCB[(size_t)(r+i)*128 + c] = f2bf(acc[i]);
        }
      }
    }
    grid.sync();
    // ================= phase A : activations + attention (per-b blocks) =================
    if (bid < 32) {
      int b = bid;
      // decoder LSTM pointwise for step t-1 (gates are zero-init at t=0 -> dh=0)
      for (int u = tid; u < 1024; u += 256) {
        float gi = GDEC[(size_t)b*4096 + u]        + dbih[u]        + dbhh[u];
        float gf = GDEC[(size_t)b*4096 + 1024 + u] + dbih[1024+u]   + dbhh[1024+u];
        float gg = GDEC[(size_t)b*4096 + 2048 + u] + dbih[2048+u]   + dbhh[2048+u];
        float go = GDEC[(size_t)b*4096 + 3072 + u] + dbih[3072+u]   + dbhh[3072+u];
        float c0 = DC[b*1024+u];
        float c2 = sigm(gf)*c0 + sigm(gi)*tanhx(gg);
        float h2 = sigm(go)*tanhx(c2);
        DC[b*1024+u] = c2;
        u16 hb = f2bf(h2);
        ADEC[(size_t)b*KDEC + 1536 + u] = hb;                       // for dec GEMM of step t
        APROJ[(size_t)((t+1)&1)*32*1536 + (size_t)b*1536 + u] = hb; // dh_{t-1} -> slot (t-1)&1
      }
      // attention LSTM pointwise for step t
      if (t < TOUT) {
        for (int u = tid; u < 1024; u += 256) {
          float gi = GATT[(size_t)b*4096 + u]        + abih[u]      + abhh[u];
          float gf = GATT[(size_t)b*4096 + 1024 + u] + abih[1024+u] + abhh[1024+u];
          float gg = GATT[(size_t)b*4096 + 2048 + u] + abih[2048+u] + abhh[2048+u];
          float go = GATT[(size_t)b*4096 + 3072 + u] + abih[3072+u] + abhh[3072+u];
          float c0 = AC[b*1024+u];
          float c2 = sigm(gf)*c0 + sigm(gi)*tanhx(gg);
          float h2 = sigm(go)*tanhx(c2);
          AC[b*1024+u] = c2;
          sAh[u] = h2;
          u16 hb = f2bf(h2);
          ADEC[(size_t)b*KDEC + u] = hb;         // ah_t for dec GEMM
          AATT[(size_t)b*KATT + 768 + u] = hb;   // ah_t for att GEMM of t+1
        }
      }
      __syncthreads();
      // pq = ah . wq^T (fp32)
      if (t < TOUT) {
        int a = tid & 127, half = tid >> 7;
        const float4* wqr = (const float4*)(wq + (size_t)a*1024 + half*512);
        float s = 0.f;
        for (int j = 0; j < 128; ++j) {
          float4 w4 = wqr[j];
          float4 h4 = *(const float4*)&sAh[half*512 + j*4];
          s += w4.x*h4.x + w4.y*h4.y + w4.z*h4.z + w4.w*h4.w;
        }
        sPq[half][a] = s;
      }
      __syncthreads();
      if (t < TOUT && tid < 128) sPq[0][tid] += sPq[1][tid];
      __syncthreads();
      // energies
      if (t < TOUT) {
        for (int tt = tid; tt < 512; tt += 256) {
          const u16* pmr = PMB  + (size_t)(b*512+tt)*128;
          const u16* lor = LOCB + (size_t)(b*512+tt)*128;
          float s = 0.f;
          for (int a = 0; a < 128; a += 2) {
            unsigned pm2 = *(const unsigned*)(pmr + a);
            unsigned lo2 = *(const unsigned*)(lor + a);
            float x0 = sPq[0][a]   + bf2f((u16)pm2)       + bf2f((u16)lo2);
            float x1 = sPq[0][a+1] + bf2f((u16)(pm2>>16)) + bf2f((u16)(lo2>>16));
            s += vv[a]*tanhx(x0) + vv[a+1]*tanhx(x1);
          }
          sE[tt] = s;
        }
      }
      __syncthreads();
      // softmax + state/output writes
      if (t < TOUT) {
        float m0 = fmaxf(sE[tid], sE[tid+256]);
        sRed[tid] = m0; __syncthreads();
        for (int s = 128; s > 0; s >>= 1) { if (tid < s) sRed[tid] = fmaxf(sRed[tid], sRed[tid+s]); __syncthreads(); }
        float mx = sRed[0]; __syncthreads();
        float e0 = __expf(sE[tid]-mx), e1 = __expf(sE[tid+256]-mx);
        sRed[tid] = e0+e1; __syncthreads();
        for (int s = 128; s > 0; s >>= 1) { if (tid < s) sRed[tid] += sRed[tid+s]; __syncthreads(); }
        float inv = 1.f/sRed[0];
        float w0 = e0*inv, w1 = e1*inv;
        AW2[b*512+tid] = w0;      AW2[b*512+256+tid] = w1;
        AWC[b*512+tid] += w0;     AWC[b*512+256+tid] += w1;
        out_aln[((size_t)b*500 + t)*512 + tid] = w0;
        out_aln[((size_t)b*500 + t)*512 + 256 + tid] = w1;
      }
    }
    grid.sync();
    // ================= phase C : proj GEMM (t-1), context, operand assembly =================
    if (t >= 1) {
      int gw = bid*4 + wv;
      if (gw < 12) { // proj+gate GEMM for step t-1
        int nt = gw >> 1, mt = gw & 1;
        const u16* AP = APROJ + (size_t)((t-1)&1)*32*1536;
        f32x4 acc = {0.f,0.f,0.f,0.f};
        acc = gemm_tile(AP, 1536, PGW, 1536, mt*16, nt*16, 1536, acc);
        int r = mt*16 + ((ln>>4)<<2), c = nt*16 + (ln&15);
        #pragma unroll
        for (int i = 0; i < 4; ++i) {
          int bb = r+i;
          if (c < 80)       out_mel[((size_t)bb*80 + c)*500 + (t-1)] = acc[i] + pb[c];
          else if (c == 80) out_gate[(size_t)bb*500 + (t-1)] = acc[i] + gb[0];
        }
      }
    }
    if (t < TOUT) {
      // context: 512 (b, e-tile) tasks over 256 blocks
      for (int rep = 0; rep < 2; ++rep) {
        int task = bid*2 + rep;
        int b = task >> 4, ec = task & 15;
        int el = tid & 31, tg = tid >> 5;
        int e = ec*32 + el;
        const u16* mr = MEMB + (size_t)b*512*512 + e;
        float part = 0.f;
        for (int tt = tg; tt < 512; tt += 8) part += AW2[b*512+tt] * bf2f(mr[(size_t)tt*512]);
        sC[tg][el] = part;
        __syncthreads();
        if (tid < 32) {
          float s = 0.f;
          #pragma unroll
          for (int r8 = 0; r8 < 8; ++r8) s += sC[r8][tid];
          int ee = ec*32 + tid;
          u16 cb = f2bf(s);
          ADEC[(size_t)b*KDEC + 1024 + ee] = cb;
          AATT[(size_t)b*KATT + 256 + ee] = cb;
          APROJ[(size_t)(t&1)*32*1536 + (size_t)b*1536 + 1024 + ee] = cb;
        }
        __syncthreads();
      }
      // build A_loc rows (aw / awc windows) for step t+1
      {
        int r0 = bid*64;
        for (int x = tid; x < 64*64; x += 256) {
          int rr = r0 + (x>>6), k = x&63;
          int bb = rr>>9, tt = rr&511;
          float val = 0.f;
          if (k < 31)      { int ts = tt + k - 15; if (ts >= 0 && ts < 512) val = AW2[bb*512+ts]; }
          else if (k < 62) { int ts = tt + k - 46; if (ts >= 0 && ts < 512) val = AWC[bb*512+ts]; }
          ALOC[(size_t)rr*64 + k] = f2bf(val);
        }
      }
      // copy next prenet frame into A_att
      if ((bid&7)==0 && (t+1) < TOUT) {
        int b = bid>>3;
        AATT[(size_t)b*KATT + tid] = PREB[((size_t)(t+1)*32 + b)*256 + tid];
      }
    }
    grid.sync();
  }
}

// ---------------- host ----------------
extern "C" void kernel_launch(void* const* d_in, const int* in_sizes, int n_in,
                              void* d_out, int out_size, void* d_ws, size_t ws_size,
                              hipStream_t stream) {
  const float* memory = (const float*)d_in[0];
  const float* mels   = (const float*)d_in[1];
  const float* pw1    = (const float*)d_in[2];
  const float* pw2    = (const float*)d_in[3];
  const float* awih   = (const float*)d_in[4];
  const float* awhh   = (const float*)d_in[5];
  const float* abih   = (const float*)d_in[6];
  const float* abhh   = (const float*)d_in[7];
  const float* wq     = (const float*)d_in[8];
  const float* wm     = (const float*)d_in[9];
  const float* vv     = (const float*)d_in[10];
  const float* lcw    = (const float*)d_in[11];
  const float* ldw    = (const float*)d_in[12];
  const float* dwih   = (const float*)d_in[13];
  const float* dwhh   = (const float*)d_in[14];
  const float* dbih   = (const float*)d_in[15];
  const float* dbhh   = (const float*)d_in[16];
  const float* prw    = (const float*)d_in[17];
  const float* prb    = (const float*)d_in[18];
  const float* gw     = (const float*)d_in[19];
  const float* gb     = (const float*)d_in[20];
  char* ws = (char*)d_ws;
  float* outp = (float*)d_out;

  hipLaunchKernelGGL(k_build_watt, dim3(4096), dim3(256), 0, stream, ws, awih, awhh);
  hipLaunchKernelGGL(k_build_wdec, dim3(4096), dim3(256), 0, stream, ws, dwih, dwhh);
  hipLaunchKernelGGL(k_cvt, dim3(2048), dim3(256), 0, stream, (u16*)(ws+OMEMB), memory, (long)32*512*512);
  hipLaunchKernelGGL(k_cvt, dim3(256), dim3(256), 0, stream, (u16*)(ws+OWMB), wm, (long)128*512);
  hipLaunchKernelGGL(k_cvt, dim3(256), dim3(256), 0, stream, (u16*)(ws+OW2B), pw2, (long)256*256);
  hipLaunchKernelGGL(k_build_w1, dim3(256), dim3(128), 0, stream, ws, pw1);
  hipLaunchKernelGGL(k_build_pgw, dim3(96), dim3(256), 0, stream, ws, prw, gw);
  hipLaunchKernelGGL(k_build_ax, dim3(2048), dim3(256), 0, stream, ws, mels);
  hipLaunchKernelGGL(k_build_mk, dim3(32), dim3(256), 0, stream, ws, ldw, lcw);
  // pm = memory . wm^T   [16384 x 128], K=512
  hipLaunchKernelGGL(k_gemm_pre, dim3(1024), dim3(256), 0, stream,
    (const u16*)(ws+OMEMB), 512, (const u16*)(ws+OWMB), 512, 8, 512, (u16*)(ws+OPMB), 128, 0);
  // prenet layer 1: [16000 x 256], K=96 (padded 80)
  hipLaunchKernelGGL(k_gemm_pre, dim3(1000), dim3(256), 0, stream,
    (const u16*)(ws+OAXB), 96, (const u16*)(ws+OW1B), 96, 16, 96, (u16*)(ws+OH1B), 256, 1);
  // prenet layer 2: [16000 x 256], K=256
  hipLaunchKernelGGL(k_gemm_pre, dim3(1000), dim3(256), 0, stream,
    (const u16*)(ws+OH1B), 256, (const u16*)(ws+OW2B), 256, 16, 256, (u16*)(ws+OPREB), 256, 1);
  hipLaunchKernelGGL(k_zero, dim3(2048), dim3(256), 0, stream, ws);
  hipLaunchKernelGGL(k_pre0, dim3(32), dim3(256), 0, stream, ws);

  void* ka[10];
  ka[0] = (void*)&ws;   ka[1] = (void*)&wq;   ka[2] = (void*)&vv;
  ka[3] = (void*)&abih; ka[4] = (void*)&abhh; ka[5] = (void*)&dbih;
  ka[6] = (void*)&dbhh; ka[7] = (void*)&prb;  ka[8] = (void*)&gb;
  ka[9] = (void*)&outp;
  hipLaunchCooperativeKernel((void*)k_main, dim3(256), dim3(256), ka, 0, stream);
}